// Round 10
// baseline (463.570 us; speedup 1.0000x reference)
//
#include <hip/hip_runtime.h>

#define NN 50000
#define NE 800000
#define DD 128
#define D4 32        // float4s per row
#define NBUCK 196    // ceil(NN/256) node buckets
#define CAP 5120     // staging capacity per bucket
#define BIN_EDGES 2048

typedef __attribute__((ext_vector_type(8))) short short8;
typedef __attribute__((ext_vector_type(4))) float f32x4;

__device__ __forceinline__ unsigned short f2bf(float f) {
    unsigned u = __float_as_uint(f);
    unsigned r = u + 0x7FFF + ((u >> 16) & 1);  // RTN-even
    return (unsigned short)(r >> 16);
}
__device__ __forceinline__ float bf2f(unsigned short s) {
    return __uint_as_float(((unsigned)s) << 16);
}

// ------- fused setup: xb = bf16(x_in) | Wt prep | bcur init | stats zero -------

#define X2B_NB 6250   // NN*D4 / 256
#define WT_NB 384     // 6*16384 / 256

__global__ void setup_kernel(const float4* __restrict__ xin, const float* __restrict__ W1,
                             const float* __restrict__ W2, ushort4* __restrict__ xb,
                             unsigned short* __restrict__ Wt, int* __restrict__ bcur,
                             float* __restrict__ stats) {
    int bid = blockIdx.x;
    int tid = threadIdx.x;
    if (bid < X2B_NB) {
        int i = bid * 256 + tid;
        float4 v = xin[i];
        ushort4 o;
        o.x = f2bf(v.x); o.y = f2bf(v.y); o.z = f2bf(v.z); o.w = f2bf(v.w);
        xb[i] = o;
    } else if (bid < X2B_NB + WT_NB) {
        int i = (bid - X2B_NB) * 256 + tid;  // Wt[m][n][k] = bf16(W[m][k][n])
        int m = i >> 14;
        int r = i & 16383;
        int n = r >> 7;
        int k = r & 127;
        const float* Ws = (m < 3) ? (W1 + m * 16384) : (W2 + (m - 3) * 16384);
        Wt[i] = f2bf(Ws[k * 128 + n]);
    } else {
        if (tid < NBUCK) bcur[tid] = tid * CAP;
        stats[tid] = 0.f;          // 3 layer slices of 256 floats
        stats[256 + tid] = 0.f;
        stats[512 + tid] = 0.f;
    }
}

// ---------------- CSR build: bucket counting sort ----------------
// R6 lesson: line writebacks are per-line regardless of element size; a line's
// writers must live in ONE block within a short window. R7 lesson: big LDS
// staging + tiny grid starves occupancy. Shape: per-block direct stores into
// per-bucket reserved runs (block-private ~80B runs merge in L2).

__global__ void __launch_bounds__(256) bin_pass(const int* __restrict__ ei,
                                                const float* __restrict__ ew,
                                                int* __restrict__ bcur,
                                                int2* __restrict__ staging) {
    __shared__ int cnt[256], base[256], cur[256];
    int tid = threadIdx.x;
    int e0 = blockIdx.x * BIN_EDGES;
    int ne = NE - e0; if (ne > BIN_EDGES) ne = BIN_EDGES;
    cnt[tid] = 0;
    cur[tid] = 0;
    __syncthreads();
    int dstv[BIN_EDGES / 256];
    unsigned packv[BIN_EDGES / 256];
#pragma unroll
    for (int j = 0; j < BIN_EDGES / 256; j++) {
        int i = j * 256 + tid;
        dstv[j] = -1;
        if (i < ne) {
            int e = e0 + i;
            int dst = ei[NE + e];
            dstv[j] = dst;
            packv[j] = (((unsigned)ei[e]) << 16) | (unsigned)f2bf(ew[e]);
            atomicAdd(&cnt[dst >> 8], 1);
        }
    }
    __syncthreads();
    if (tid < NBUCK && cnt[tid] > 0) base[tid] = atomicAdd(&bcur[tid], cnt[tid]);
    __syncthreads();
#pragma unroll
    for (int j = 0; j < BIN_EDGES / 256; j++) {
        int dst = dstv[j];
        if (dst >= 0) {
            int b = dst >> 8;
            int p = atomicAdd(&cur[b], 1);
            staging[base[b] + p] = make_int2((int)packv[j], dst & 255);
        }
    }
}

// one bucket per block; inlines the bucket-count scan (196 redundant loads,
// trivial) to avoid a separate scan launch; emits rowptr + srcw coalesced.
__global__ void __launch_bounds__(256) place_pass(const int2* __restrict__ staging,
                                                  const int* __restrict__ bcur,
                                                  int* __restrict__ rowptr,
                                                  unsigned* __restrict__ srcw) {
    __shared__ int hist[256], off[256], cur[256], sb[256];
    __shared__ unsigned outb[CAP];  // 20 KB
    int b = blockIdx.x;
    int tid = threadIdx.x;
    // scan all bucket counts to get this bucket's CSR base
    int c0 = (tid < NBUCK) ? (bcur[tid] - tid * CAP) : 0;
    sb[tid] = c0;
    __syncthreads();
    for (int o = 1; o < 256; o <<= 1) {
        int v = sb[tid];
        int add = (tid >= o) ? sb[tid - o] : 0;
        __syncthreads();
        sb[tid] = v + add;
        __syncthreads();
    }
    int bucketBase = (b == 0) ? 0 : sb[b - 1];
    int sbase = b * CAP;
    int nb = bcur[b] - sbase;
    hist[tid] = 0;
    __syncthreads();
    for (int i = tid; i < nb; i += 256) atomicAdd(&hist[staging[sbase + i].y], 1);
    __syncthreads();
    off[tid] = hist[tid];
    __syncthreads();
    for (int o = 1; o < 256; o <<= 1) {
        int v = off[tid];
        int add = (tid >= o) ? off[tid - o] : 0;
        __syncthreads();
        off[tid] = v + add;
        __syncthreads();
    }
    int excl = off[tid] - hist[tid];
    cur[tid] = excl;
    int node = b * 256 + tid;
    if (node < NN) rowptr[node] = bucketBase + excl;
    if (b == 0 && tid == 0) rowptr[NN] = NE;
    __syncthreads();
    for (int i = tid; i < nb; i += 256) {
        int2 r = staging[sbase + i];
        int p = atomicAdd(&cur[r.y], 1);
        outb[p] = (unsigned)r.x;
    }
    __syncthreads();
    for (int i = tid; i < nb; i += 256) srcw[bucketBase + i] = outb[i];
}

// ---------------- fused layer: gather -> LDS -> gemm1 -> relu -> gemm2 ----------------
// Each block owns 64 node rows: gathers g = bf16((1+eps)*xb + sum w*xb[src])
// straight into the swizzled As tile (no global g buffer), then runs the MLP.
// hb = bf16(relu(g@W1^T+b1)@W2^T+b2), BN col sums/sumsq -> stats slice.

#define GM 64  // rows per block

__global__ void __launch_bounds__(256) layer_kernel(
    const unsigned short* __restrict__ xb, const unsigned* __restrict__ srcw,
    const int* __restrict__ rowptr, const float* __restrict__ epsp,
    const unsigned short* __restrict__ Wt1, const unsigned short* __restrict__ Wt2,
    const float* __restrict__ b1, const float* __restrict__ b2,
    unsigned short* __restrict__ outB, float* __restrict__ stats) {
    __shared__ unsigned short As[GM * 128];  // 16 KB
    __shared__ unsigned short Ts[GM * 128];  // 16 KB

    int tid = threadIdx.x;
    int wave = tid >> 6;
    int lane = tid & 63;
    int q = lane >> 4;    // quad 0..3
    int ml = lane & 15;
    int r0 = blockIdx.x * GM;

    // weight fragments issued FIRST so their latency hides under the gather
    short8 Bf1[2][4], Bf2[2][4];
#pragma unroll
    for (int t = 0; t < 2; t++)
#pragma unroll
        for (int ks = 0; ks < 4; ks++) {
            int n = wave * 32 + t * 16 + ml;
            Bf1[t][ks] = *(const short8*)(Wt1 + n * DD + ks * 32 + q * 8);
            Bf2[t][ks] = *(const short8*)(Wt2 + n * DD + ks * 32 + q * 8);
        }
    float bvl1[2] = {b1[wave * 32 + ml], b1[wave * 32 + 16 + ml]};
    float bvl2[2] = {b2[wave * 32 + ml], b2[wave * 32 + 16 + ml]};

    // ---- gather phase: 8 lane-groups of 32, 8 nodes each ----
    int grp = tid >> 5;
    int gl = tid & 31;
    float epsv = 1.0f + *epsp;
    const ushort4* xb4 = (const ushort4*)xb;
    for (int j = 0; j < 8; j++) {
        int row = grp * 8 + j;
        int node = r0 + row;
        float4 acc = make_float4(0.f, 0.f, 0.f, 0.f);
        if (node < NN) {
            ushort4 xv = xb4[node * D4 + gl];
            acc = make_float4(bf2f(xv.x) * epsv, bf2f(xv.y) * epsv,
                              bf2f(xv.z) * epsv, bf2f(xv.w) * epsv);
            int beg = rowptr[node], end = rowptr[node + 1];
            int i = beg;
            for (; i + 3 < end; i += 4) {
                unsigned sw0 = srcw[i], sw1 = srcw[i + 1], sw2 = srcw[i + 2], sw3 = srcw[i + 3];
                ushort4 p0 = xb4[(sw0 >> 16) * D4 + gl];
                ushort4 p1 = xb4[(sw1 >> 16) * D4 + gl];
                ushort4 p2 = xb4[(sw2 >> 16) * D4 + gl];
                ushort4 p3 = xb4[(sw3 >> 16) * D4 + gl];
                float w0 = bf2f((unsigned short)(sw0 & 0xffff));
                float w1 = bf2f((unsigned short)(sw1 & 0xffff));
                float w2 = bf2f((unsigned short)(sw2 & 0xffff));
                float w3 = bf2f((unsigned short)(sw3 & 0xffff));
                acc.x += bf2f(p0.x) * w0; acc.y += bf2f(p0.y) * w0;
                acc.z += bf2f(p0.z) * w0; acc.w += bf2f(p0.w) * w0;
                acc.x += bf2f(p1.x) * w1; acc.y += bf2f(p1.y) * w1;
                acc.z += bf2f(p1.z) * w1; acc.w += bf2f(p1.w) * w1;
                acc.x += bf2f(p2.x) * w2; acc.y += bf2f(p2.y) * w2;
                acc.z += bf2f(p2.z) * w2; acc.w += bf2f(p2.w) * w2;
                acc.x += bf2f(p3.x) * w3; acc.y += bf2f(p3.y) * w3;
                acc.z += bf2f(p3.z) * w3; acc.w += bf2f(p3.w) * w3;
            }
            for (; i < end; i++) {
                unsigned sw = srcw[i];
                ushort4 p = xb4[(sw >> 16) * D4 + gl];
                float w = bf2f((unsigned short)(sw & 0xffff));
                acc.x += bf2f(p.x) * w; acc.y += bf2f(p.y) * w;
                acc.z += bf2f(p.z) * w; acc.w += bf2f(p.w) * w;
            }
        }
        // store bf16 row into As with the 16B-chunk XOR swizzle (chunk c = gl>>1)
        ushort4 o;
        o.x = f2bf(acc.x); o.y = f2bf(acc.y); o.z = f2bf(acc.z); o.w = f2bf(acc.w);
        int cs = (gl >> 1) ^ (row & 15);
        *(ushort4*)(&As[row * DD + cs * 8 + (gl & 1) * 4]) = o;
    }
    __syncthreads();

    // ---- gemm1: t = relu(As @ W1^T + b1) -> Ts (bf16, swizzled) ----
    for (int rt = 0; rt < GM / 16; rt++) {
        int arow = rt * 16 + ml;
        short8 Af[4];
#pragma unroll
        for (int ks = 0; ks < 4; ks++) {
            int cs = (ks * 4 + q) ^ (arow & 15);
            Af[ks] = *(const short8*)(&As[arow * DD + cs * 8]);
        }
        f32x4 acc[2] = {{0.f, 0.f, 0.f, 0.f}, {0.f, 0.f, 0.f, 0.f}};
#pragma unroll
        for (int ks = 0; ks < 4; ks++) {
            acc[0] = __builtin_amdgcn_mfma_f32_16x16x32_bf16(Af[ks], Bf1[0][ks], acc[0], 0, 0, 0);
            acc[1] = __builtin_amdgcn_mfma_f32_16x16x32_bf16(Af[ks], Bf1[1][ks], acc[1], 0, 0, 0);
        }
        // C/D layout: col=lane&15, row=quad*4+reg [m89-verified]
#pragma unroll
        for (int t = 0; t < 2; t++) {
            int col = wave * 32 + t * 16 + ml;
#pragma unroll
            for (int r = 0; r < 4; r++) {
                int lrow = rt * 16 + q * 4 + r;
                unsigned short u = f2bf(fmaxf(acc[t][r] + bvl1[t], 0.f));
                Ts[lrow * DD + ((((col >> 3) ^ (lrow & 15)) << 3) | (col & 7))] = u;
            }
        }
    }
    __syncthreads();

    // ---- gemm2: h = t @ W2^T + b2 -> global bf16 + BN stats ----
    float s[2] = {0.f, 0.f}, s2[2] = {0.f, 0.f};
    for (int rt = 0; rt < GM / 16; rt++) {
        int arow = rt * 16 + ml;
        short8 Af[4];
#pragma unroll
        for (int ks = 0; ks < 4; ks++) {
            int cs = (ks * 4 + q) ^ (arow & 15);
            Af[ks] = *(const short8*)(&Ts[arow * DD + cs * 8]);
        }
        f32x4 acc[2] = {{0.f, 0.f, 0.f, 0.f}, {0.f, 0.f, 0.f, 0.f}};
#pragma unroll
        for (int ks = 0; ks < 4; ks++) {
            acc[0] = __builtin_amdgcn_mfma_f32_16x16x32_bf16(Af[ks], Bf2[0][ks], acc[0], 0, 0, 0);
            acc[1] = __builtin_amdgcn_mfma_f32_16x16x32_bf16(Af[ks], Bf2[1][ks], acc[1], 0, 0, 0);
        }
#pragma unroll
        for (int t = 0; t < 2; t++) {
            int col = wave * 32 + t * 16 + ml;
#pragma unroll
            for (int r = 0; r < 4; r++) {
                int grow = r0 + rt * 16 + q * 4 + r;
                if (grow < NN) {
                    float v = acc[t][r] + bvl2[t];
                    outB[grow * DD + col] = f2bf(v);
                    s[t] += v;
                    s2[t] += v * v;
                }
            }
        }
    }

#pragma unroll
    for (int t = 0; t < 2; t++) {
        float a = s[t], b = s2[t];
        a += __shfl_xor(a, 16); b += __shfl_xor(b, 16);
        a += __shfl_xor(a, 32); b += __shfl_xor(b, 32);
        if (q == 0) {
            int col = wave * 32 + t * 16 + ml;
            atomicAdd(&stats[col], a);
            atomicAdd(&stats[DD + col], b);
        }
    }
}

// -------- BN apply + ReLU + residual (bf16 chain):
//   xb_out = bf16(xb_in + relu(bn(hb)));  last layer writes fp32 x. --------

__global__ void bn_apply(const unsigned short* __restrict__ hb, const float* __restrict__ stats,
                         const float* __restrict__ gamma, const float* __restrict__ beta,
                         const unsigned short* __restrict__ xbin, ushort4* __restrict__ xbout,
                         float4* __restrict__ xf32) {
    int i = blockIdx.x * blockDim.x + threadIdx.x;
    if (i >= NN * D4) return;
    int c4 = i & 31;
    const float invN = 1.0f / NN;
    float4 s = ((const float4*)stats)[c4];
    float4 s2 = ((const float4*)stats)[D4 + c4];
    float4 mu = make_float4(s.x * invN, s.y * invN, s.z * invN, s.w * invN);
    float4 var = make_float4(s2.x * invN - mu.x * mu.x, s2.y * invN - mu.y * mu.y,
                             s2.z * invN - mu.z * mu.z, s2.w * invN - mu.w * mu.w);
    float4 inv = make_float4(rsqrtf(var.x + 1e-5f), rsqrtf(var.y + 1e-5f),
                             rsqrtf(var.z + 1e-5f), rsqrtf(var.w + 1e-5f));
    float4 g = ((const float4*)gamma)[c4];
    float4 b = ((const float4*)beta)[c4];
    ushort4 hu = ((const ushort4*)hb)[i];
    float4 hv = make_float4(bf2f(hu.x), bf2f(hu.y), bf2f(hu.z), bf2f(hu.w));
    ushort4 xu = ((const ushort4*)xbin)[i];
    float4 xv = make_float4(bf2f(xu.x), bf2f(xu.y), bf2f(xu.z), bf2f(xu.w));
    float4 v = make_float4(fmaxf(g.x * (hv.x - mu.x) * inv.x + b.x, 0.f),
                           fmaxf(g.y * (hv.y - mu.y) * inv.y + b.y, 0.f),
                           fmaxf(g.z * (hv.z - mu.z) * inv.z + b.z, 0.f),
                           fmaxf(g.w * (hv.w - mu.w) * inv.w + b.w, 0.f));
    float4 o = make_float4(xv.x + v.x, xv.y + v.y, xv.z + v.z, xv.w + v.w);
    if (xbout) {
        ushort4 ob;
        ob.x = f2bf(o.x); ob.y = f2bf(o.y); ob.z = f2bf(o.z); ob.w = f2bf(o.w);
        xbout[i] = ob;
    }
    if (xf32) xf32[i] = o;
}

// ---------------- launcher ----------------

extern "C" void kernel_launch(void* const* d_in, const int* in_sizes, int n_in,
                              void* d_out, int out_size, void* d_ws, size_t ws_size,
                              hipStream_t stream) {
    const float* x_in = (const float*)d_in[0];
    const int* ei = (const int*)d_in[1];
    // d_in[2] = edge_attr (unused)
    const float* ew = (const float*)d_in[3];
    const float* W1 = (const float*)d_in[4];
    const float* b1 = (const float*)d_in[5];
    const float* W2 = (const float*)d_in[6];
    const float* b2 = (const float*)d_in[7];
    const float* eps = (const float*)d_in[8];
    const float* gamma = (const float*)d_in[9];
    const float* beta = (const float*)d_in[10];

    float* x = (float*)d_out;  // final fp32 output

    char* ws = (char*)d_ws;
    unsigned short* hb = (unsigned short*)ws;              // MLP out bf16   (12.8 MB)
    int2* staging = (int2*)ws;                             // CSR staging 8.03 MB, overlays hb
    unsigned short* xb = (unsigned short*)(ws + 12800000); // running x bf16 (12.8 MB)
    float* stats = (float*)(ws + 25600000);                // 3 x 256 floats (per-layer)
    int* rowptr = (int*)(ws + 25603072);                   // 50001 ints
    unsigned short* Wtall = (unsigned short*)(ws + 25803264);  // 6*16384 bf16
    unsigned* srcw = (unsigned*)(ws + 25999872);           // 800000 uint (src<<16 | bf16 w)
    int* bcur = (int*)(ws + 29199872);                     // 196 ints (staging cursors)

    const int n4x = NN * D4;

    // fused setup: xb mirror, weight transpose, bcur init, stats zero
    setup_kernel<<<X2B_NB + WT_NB + 1, 256, 0, stream>>>(
        (const float4*)x_in, W1, W2, (ushort4*)xb, Wtall, bcur, stats);

    // ---- CSR build: bucket counting sort ----
    bin_pass<<<(NE + BIN_EDGES - 1) / BIN_EDGES, 256, 0, stream>>>(ei, ew, bcur, staging);
    place_pass<<<NBUCK, 256, 0, stream>>>(staging, bcur, rowptr, srcw);

    const int gemmGrid = (NN + GM - 1) / GM;  // 782

    for (int i = 0; i < 3; i++) {
        const unsigned short* Wt1 = Wtall + i * 16384;
        const unsigned short* Wt2 = Wtall + (3 + i) * 16384;
        float* statsL = stats + i * 256;

        // gather + MLP fused: hb = bf16(relu(g@W1+b1)@W2+b2), BN stats
        layer_kernel<<<gemmGrid, 256, 0, stream>>>(
            xb, srcw, rowptr, eps + i, Wt1, Wt2, b1 + i * DD, b2 + i * DD, hb, statsL);

        // xb = bf16(xb + relu(bn(hb))); layer 2 also writes fp32 x
        bn_apply<<<(n4x + 255) / 256, 256, 0, stream>>>(
            hb, statsL, gamma + i * DD, beta + i * DD, xb,
            (i < 2) ? (ushort4*)xb : nullptr,
            (i == 2) ? (float4*)x : nullptr);
    }
}

// Round 11
// 349.541 us; speedup vs baseline: 1.3262x; 1.3262x over previous
//
#include <hip/hip_runtime.h>

#define NN 50000
#define NE 800000
#define DD 128
#define D4 32        // float4s per row
#define NBUCK 196    // ceil(NN/256) node buckets
#define CAP 5120     // staging capacity per bucket
#define BIN_EDGES 2048

typedef __attribute__((ext_vector_type(8))) short short8;
typedef __attribute__((ext_vector_type(4))) float f32x4;

__device__ __forceinline__ unsigned short f2bf(float f) {
    unsigned u = __float_as_uint(f);
    unsigned r = u + 0x7FFF + ((u >> 16) & 1);  // RTN-even
    return (unsigned short)(r >> 16);
}
__device__ __forceinline__ float bf2f(unsigned short s) {
    return __uint_as_float(((unsigned)s) << 16);
}

// ------- fused setup: xb = bf16(x_in) | Wt prep | bcur init | stats zero -------

#define X2B_NB 6250   // NN*D4 / 256
#define WT_NB 384     // 6*16384 / 256

__global__ void setup_kernel(const float4* __restrict__ xin, const float* __restrict__ W1,
                             const float* __restrict__ W2, ushort4* __restrict__ xb,
                             unsigned short* __restrict__ Wt, int* __restrict__ bcur,
                             float* __restrict__ stats) {
    int bid = blockIdx.x;
    int tid = threadIdx.x;
    if (bid < X2B_NB) {
        int i = bid * 256 + tid;
        float4 v = xin[i];
        ushort4 o;
        o.x = f2bf(v.x); o.y = f2bf(v.y); o.z = f2bf(v.z); o.w = f2bf(v.w);
        xb[i] = o;
    } else if (bid < X2B_NB + WT_NB) {
        int i = (bid - X2B_NB) * 256 + tid;  // Wt[m][n][k] = bf16(W[m][k][n])
        int m = i >> 14;
        int r = i & 16383;
        int n = r >> 7;
        int k = r & 127;
        const float* Ws = (m < 3) ? (W1 + m * 16384) : (W2 + (m - 3) * 16384);
        Wt[i] = f2bf(Ws[k * 128 + n]);
    } else {
        if (tid < NBUCK) bcur[tid] = tid * CAP;
        stats[tid] = 0.f;          // 3 layer slices of 256 floats
        stats[256 + tid] = 0.f;
        stats[512 + tid] = 0.f;
    }
}

// ---------------- CSR build: bucket counting sort ----------------
// R6 lesson: scattered sub-line stores cost a full 64B line-writeback each;
// a line's writers must live in ONE block within a short window. R7 lesson:
// big LDS staging + tiny grid starves occupancy. Shape: per-block direct
// stores into per-bucket reserved runs (block-private ~80B runs merge in L2).

__global__ void __launch_bounds__(256) bin_pass(const int* __restrict__ ei,
                                                const float* __restrict__ ew,
                                                int* __restrict__ bcur,
                                                int2* __restrict__ staging) {
    __shared__ int cnt[256], base[256], cur[256];
    int tid = threadIdx.x;
    int e0 = blockIdx.x * BIN_EDGES;
    int ne = NE - e0; if (ne > BIN_EDGES) ne = BIN_EDGES;
    cnt[tid] = 0;
    cur[tid] = 0;
    __syncthreads();
    int dstv[BIN_EDGES / 256];
    unsigned packv[BIN_EDGES / 256];
#pragma unroll
    for (int j = 0; j < BIN_EDGES / 256; j++) {
        int i = j * 256 + tid;
        dstv[j] = -1;
        if (i < ne) {
            int e = e0 + i;
            int dst = ei[NE + e];
            dstv[j] = dst;
            packv[j] = (((unsigned)ei[e]) << 16) | (unsigned)f2bf(ew[e]);
            atomicAdd(&cnt[dst >> 8], 1);
        }
    }
    __syncthreads();
    if (tid < NBUCK && cnt[tid] > 0) base[tid] = atomicAdd(&bcur[tid], cnt[tid]);
    __syncthreads();
#pragma unroll
    for (int j = 0; j < BIN_EDGES / 256; j++) {
        int dst = dstv[j];
        if (dst >= 0) {
            int b = dst >> 8;
            int p = atomicAdd(&cur[b], 1);
            staging[base[b] + p] = make_int2((int)packv[j], dst & 255);
        }
    }
}

// one bucket per block; inlines the bucket-count scan to avoid a separate
// launch; emits rowptr + srcw coalesced.
__global__ void __launch_bounds__(256) place_pass(const int2* __restrict__ staging,
                                                  const int* __restrict__ bcur,
                                                  int* __restrict__ rowptr,
                                                  unsigned* __restrict__ srcw) {
    __shared__ int hist[256], off[256], cur[256], sb[256];
    __shared__ unsigned outb[CAP];  // 20 KB
    int b = blockIdx.x;
    int tid = threadIdx.x;
    int c0 = (tid < NBUCK) ? (bcur[tid] - tid * CAP) : 0;
    sb[tid] = c0;
    __syncthreads();
    for (int o = 1; o < 256; o <<= 1) {
        int v = sb[tid];
        int add = (tid >= o) ? sb[tid - o] : 0;
        __syncthreads();
        sb[tid] = v + add;
        __syncthreads();
    }
    int bucketBase = (b == 0) ? 0 : sb[b - 1];
    int sbase = b * CAP;
    int nb = bcur[b] - sbase;
    hist[tid] = 0;
    __syncthreads();
    for (int i = tid; i < nb; i += 256) atomicAdd(&hist[staging[sbase + i].y], 1);
    __syncthreads();
    off[tid] = hist[tid];
    __syncthreads();
    for (int o = 1; o < 256; o <<= 1) {
        int v = off[tid];
        int add = (tid >= o) ? off[tid - o] : 0;
        __syncthreads();
        off[tid] = v + add;
        __syncthreads();
    }
    int excl = off[tid] - hist[tid];
    cur[tid] = excl;
    int node = b * 256 + tid;
    if (node < NN) rowptr[node] = bucketBase + excl;
    if (b == 0 && tid == 0) rowptr[NN] = NE;
    __syncthreads();
    for (int i = tid; i < nb; i += 256) {
        int2 r = staging[sbase + i];
        int p = atomicAdd(&cur[r.y], 1);
        outb[p] = (unsigned)r.x;
    }
    __syncthreads();
    for (int i = tid; i < nb; i += 256) srcw[bucketBase + i] = outb[i];
}

// ---- gather + GIN combine: g[n] = bf16((1+eps)*xb[n] + sum_e w_e * xb[src_e]) ----
// 32 lanes per node, 8 nodes per 256-block (6250 blocks = 25k waves for latency
// hiding -- R10 lesson: do NOT fuse this into the GEMM tile shape).
// 8 edge-loads in flight per lane group (R11: was 4).

__global__ void __launch_bounds__(256) gather_kernel(
    const unsigned short* __restrict__ xb, const unsigned* __restrict__ srcw,
    const int* __restrict__ rowptr, const float* __restrict__ epsp,
    unsigned short* __restrict__ g) {
    int node = blockIdx.x * 8 + (threadIdx.x >> 5);
    int lane = threadIdx.x & 31;
    if (node >= NN) return;
    float epsv = 1.0f + *epsp;
    int beg = rowptr[node], end = rowptr[node + 1];
    const ushort4* xb4 = (const ushort4*)xb;
    ushort4 xv = xb4[node * D4 + lane];
    float4 acc = make_float4(bf2f(xv.x) * epsv, bf2f(xv.y) * epsv,
                             bf2f(xv.z) * epsv, bf2f(xv.w) * epsv);
    int i = beg;
    for (; i + 7 < end; i += 8) {
        ushort4 rr[8];
        float ww[8];
#pragma unroll
        for (int j = 0; j < 8; j++) {
            unsigned sw = srcw[i + j];
            rr[j] = xb4[(sw >> 16) * D4 + lane];
            ww[j] = bf2f((unsigned short)(sw & 0xffff));
        }
#pragma unroll
        for (int j = 0; j < 8; j++) {
            acc.x += bf2f(rr[j].x) * ww[j]; acc.y += bf2f(rr[j].y) * ww[j];
            acc.z += bf2f(rr[j].z) * ww[j]; acc.w += bf2f(rr[j].w) * ww[j];
        }
    }
    for (; i < end; i++) {
        unsigned sw = srcw[i];
        ushort4 r = xb4[(sw >> 16) * D4 + lane];
        float w = bf2f((unsigned short)(sw & 0xffff));
        acc.x += bf2f(r.x) * w; acc.y += bf2f(r.y) * w;
        acc.z += bf2f(r.z) * w; acc.w += bf2f(r.w) * w;
    }
    ushort4 o;
    o.x = f2bf(acc.x); o.y = f2bf(acc.y); o.z = f2bf(acc.z); o.w = f2bf(acc.w);
    ((ushort4*)g)[node * D4 + lane] = o;
}

// ---------------- fused MLP: hb = bf16(relu(g@W1^T+b1) @ W2^T + b2) + BN stats ----
// 64 rows x 128 cols per block, 4 waves; wave w owns cols [w*32, w*32+32).
// t-tile stays in LDS (swizzled); both weight sets reg-resident.

#define GM 64  // rows per block

__global__ void __launch_bounds__(256) mlp_fused(
    const unsigned short* __restrict__ A,    // g: M x 128 bf16 row-major
    const unsigned short* __restrict__ Wt1,  // 128 x 128 bf16, [n][k]
    const unsigned short* __restrict__ Wt2,
    const float* __restrict__ b1, const float* __restrict__ b2,
    unsigned short* __restrict__ outB, float* __restrict__ stats) {
    __shared__ unsigned short As[GM * 128];  // 16 KB
    __shared__ unsigned short Ts[GM * 128];  // 16 KB

    int tid = threadIdx.x;
    int wave = tid >> 6;
    int lane = tid & 63;
    int q = lane >> 4;    // quad 0..3
    int ml = lane & 15;
    int r0 = blockIdx.x * GM;

    // stage A tile (zero-pad rows >= NN), 16B-chunk XOR swizzle
#pragma unroll
    for (int i = 0; i < GM / 16; i++) {
        int idx = i * 256 + tid;
        int row = idx >> 4;
        int c = idx & 15;
        float4 v = make_float4(0.f, 0.f, 0.f, 0.f);
        int grow = r0 + row;
        if (grow < NN) v = *(const float4*)(A + grow * DD + c * 8);
        int cs = c ^ (row & 15);
        *(float4*)(&As[row * DD + cs * 8]) = v;
    }

    // weight fragments (reg-resident; 32 KB each, L2-hit)
    short8 Bf1[2][4], Bf2[2][4];
#pragma unroll
    for (int t = 0; t < 2; t++)
#pragma unroll
        for (int ks = 0; ks < 4; ks++) {
            int n = wave * 32 + t * 16 + ml;
            Bf1[t][ks] = *(const short8*)(Wt1 + n * DD + ks * 32 + q * 8);
            Bf2[t][ks] = *(const short8*)(Wt2 + n * DD + ks * 32 + q * 8);
        }
    float bvl1[2] = {b1[wave * 32 + ml], b1[wave * 32 + 16 + ml]};
    float bvl2[2] = {b2[wave * 32 + ml], b2[wave * 32 + 16 + ml]};

    __syncthreads();

    // ---- gemm1: t = relu(As @ W1^T + b1) -> Ts (bf16, swizzled) ----
    for (int rt = 0; rt < GM / 16; rt++) {
        int arow = rt * 16 + ml;
        short8 Af[4];
#pragma unroll
        for (int ks = 0; ks < 4; ks++) {
            int cs = (ks * 4 + q) ^ (arow & 15);
            Af[ks] = *(const short8*)(&As[arow * DD + cs * 8]);
        }
        f32x4 acc[2] = {{0.f, 0.f, 0.f, 0.f}, {0.f, 0.f, 0.f, 0.f}};
#pragma unroll
        for (int ks = 0; ks < 4; ks++) {
            acc[0] = __builtin_amdgcn_mfma_f32_16x16x32_bf16(Af[ks], Bf1[0][ks], acc[0], 0, 0, 0);
            acc[1] = __builtin_amdgcn_mfma_f32_16x16x32_bf16(Af[ks], Bf1[1][ks], acc[1], 0, 0, 0);
        }
        // C/D layout: col=lane&15, row=quad*4+reg [m89-verified]
#pragma unroll
        for (int t = 0; t < 2; t++) {
            int col = wave * 32 + t * 16 + ml;
#pragma unroll
            for (int r = 0; r < 4; r++) {
                int lrow = rt * 16 + q * 4 + r;
                unsigned short u = f2bf(fmaxf(acc[t][r] + bvl1[t], 0.f));
                Ts[lrow * DD + ((((col >> 3) ^ (lrow & 15)) << 3) | (col & 7))] = u;
            }
        }
    }
    __syncthreads();

    // ---- gemm2: h = t @ W2^T + b2 -> global bf16 + BN stats ----
    float s[2] = {0.f, 0.f}, s2[2] = {0.f, 0.f};
    for (int rt = 0; rt < GM / 16; rt++) {
        int arow = rt * 16 + ml;
        short8 Af[4];
#pragma unroll
        for (int ks = 0; ks < 4; ks++) {
            int cs = (ks * 4 + q) ^ (arow & 15);
            Af[ks] = *(const short8*)(&Ts[arow * DD + cs * 8]);
        }
        f32x4 acc[2] = {{0.f, 0.f, 0.f, 0.f}, {0.f, 0.f, 0.f, 0.f}};
#pragma unroll
        for (int ks = 0; ks < 4; ks++) {
            acc[0] = __builtin_amdgcn_mfma_f32_16x16x32_bf16(Af[ks], Bf2[0][ks], acc[0], 0, 0, 0);
            acc[1] = __builtin_amdgcn_mfma_f32_16x16x32_bf16(Af[ks], Bf2[1][ks], acc[1], 0, 0, 0);
        }
#pragma unroll
        for (int t = 0; t < 2; t++) {
            int col = wave * 32 + t * 16 + ml;
#pragma unroll
            for (int r = 0; r < 4; r++) {
                int grow = r0 + rt * 16 + q * 4 + r;
                if (grow < NN) {
                    float v = acc[t][r] + bvl2[t];
                    outB[grow * DD + col] = f2bf(v);
                    s[t] += v;
                    s2[t] += v * v;
                }
            }
        }
    }

#pragma unroll
    for (int t = 0; t < 2; t++) {
        float a = s[t], b = s2[t];
        a += __shfl_xor(a, 16); b += __shfl_xor(b, 16);
        a += __shfl_xor(a, 32); b += __shfl_xor(b, 32);
        if (q == 0) {
            int col = wave * 32 + t * 16 + ml;
            atomicAdd(&stats[col], a);
            atomicAdd(&stats[DD + col], b);
        }
    }
}

// -------- BN apply + ReLU + residual (bf16 chain):
//   xb_out = bf16(xb_in + relu(bn(hb)));  last layer writes fp32 x. --------

__global__ void bn_apply(const unsigned short* __restrict__ hb, const float* __restrict__ stats,
                         const float* __restrict__ gamma, const float* __restrict__ beta,
                         const unsigned short* __restrict__ xbin, ushort4* __restrict__ xbout,
                         float4* __restrict__ xf32) {
    int i = blockIdx.x * blockDim.x + threadIdx.x;
    if (i >= NN * D4) return;
    int c4 = i & 31;
    const float invN = 1.0f / NN;
    float4 s = ((const float4*)stats)[c4];
    float4 s2 = ((const float4*)stats)[D4 + c4];
    float4 mu = make_float4(s.x * invN, s.y * invN, s.z * invN, s.w * invN);
    float4 var = make_float4(s2.x * invN - mu.x * mu.x, s2.y * invN - mu.y * mu.y,
                             s2.z * invN - mu.z * mu.z, s2.w * invN - mu.w * mu.w);
    float4 inv = make_float4(rsqrtf(var.x + 1e-5f), rsqrtf(var.y + 1e-5f),
                             rsqrtf(var.z + 1e-5f), rsqrtf(var.w + 1e-5f));
    float4 g = ((const float4*)gamma)[c4];
    float4 b = ((const float4*)beta)[c4];
    ushort4 hu = ((const ushort4*)hb)[i];
    float4 hv = make_float4(bf2f(hu.x), bf2f(hu.y), bf2f(hu.z), bf2f(hu.w));
    ushort4 xu = ((const ushort4*)xbin)[i];
    float4 xv = make_float4(bf2f(xu.x), bf2f(xu.y), bf2f(xu.z), bf2f(xu.w));
    float4 v = make_float4(fmaxf(g.x * (hv.x - mu.x) * inv.x + b.x, 0.f),
                           fmaxf(g.y * (hv.y - mu.y) * inv.y + b.y, 0.f),
                           fmaxf(g.z * (hv.z - mu.z) * inv.z + b.z, 0.f),
                           fmaxf(g.w * (hv.w - mu.w) * inv.w + b.w, 0.f));
    float4 o = make_float4(xv.x + v.x, xv.y + v.y, xv.z + v.z, xv.w + v.w);
    if (xbout) {
        ushort4 ob;
        ob.x = f2bf(o.x); ob.y = f2bf(o.y); ob.z = f2bf(o.z); ob.w = f2bf(o.w);
        xbout[i] = ob;
    }
    if (xf32) xf32[i] = o;
}

// ---------------- launcher ----------------

extern "C" void kernel_launch(void* const* d_in, const int* in_sizes, int n_in,
                              void* d_out, int out_size, void* d_ws, size_t ws_size,
                              hipStream_t stream) {
    const float* x_in = (const float*)d_in[0];
    const int* ei = (const int*)d_in[1];
    // d_in[2] = edge_attr (unused)
    const float* ew = (const float*)d_in[3];
    const float* W1 = (const float*)d_in[4];
    const float* b1 = (const float*)d_in[5];
    const float* W2 = (const float*)d_in[6];
    const float* b2 = (const float*)d_in[7];
    const float* eps = (const float*)d_in[8];
    const float* gamma = (const float*)d_in[9];
    const float* beta = (const float*)d_in[10];

    float* x = (float*)d_out;  // final fp32 output

    char* ws = (char*)d_ws;
    unsigned short* g = (unsigned short*)ws;               // GIN input bf16 (12.8 MB)
    unsigned short* hb = (unsigned short*)(ws + 12800000); // MLP out bf16   (12.8 MB)
    int2* staging = (int2*)(ws + 12800000);                // CSR staging 8.03 MB, overlays hb
    unsigned short* xb = (unsigned short*)(ws + 25600000); // running x bf16 (12.8 MB)
    float* stats = (float*)(ws + 38400000);                // 3 x 256 floats (per-layer)
    int* rowptr = (int*)(ws + 38403072);                   // 50001 ints
    unsigned short* Wtall = (unsigned short*)(ws + 38603264);  // 6*16384 bf16
    unsigned* srcw = (unsigned*)(ws + 38799872);           // 800000 uint (src<<16 | bf16 w)
    int* bcur = (int*)(ws + 41999872);                     // 196 ints (staging cursors)

    const int n4x = NN * D4;

    // fused setup: xb mirror, weight transpose, bcur init, stats zero
    setup_kernel<<<X2B_NB + WT_NB + 1, 256, 0, stream>>>(
        (const float4*)x_in, W1, W2, (ushort4*)xb, Wtall, bcur, stats);

    // ---- CSR build: bucket counting sort ----
    bin_pass<<<(NE + BIN_EDGES - 1) / BIN_EDGES, 256, 0, stream>>>(ei, ew, bcur, staging);
    place_pass<<<NBUCK, 256, 0, stream>>>(staging, bcur, rowptr, srcw);

    const int gemmGrid = (NN + GM - 1) / GM;  // 782

    for (int i = 0; i < 3; i++) {
        const unsigned short* Wt1 = Wtall + i * 16384;
        const unsigned short* Wt2 = Wtall + (3 + i) * 16384;
        float* statsL = stats + i * 256;

        // g = bf16((1+eps)*xb + sum w*xb[src])
        gather_kernel<<<(NN + 7) / 8, 256, 0, stream>>>(xb, srcw, rowptr, eps + i, g);

        // hb = bf16(relu(g@W1+b1)@W2+b2), + BN stats
        mlp_fused<<<gemmGrid, 256, 0, stream>>>(g, Wt1, Wt2, b1 + i * DD, b2 + i * DD, hb, statsL);

        // xb = bf16(xb + relu(bn(hb))); layer 2 also writes fp32 x
        bn_apply<<<(n4x + 255) / 256, 256, 0, stream>>>(
            hb, statsL, gamma + i * DD, beta + i * DD, xb,
            (i < 2) ? (ushort4*)xb : nullptr,
            (i == 2) ? (float4*)x : nullptr);
    }
}